// Round 1
// baseline (643.350 us; speedup 1.0000x reference)
//
#include <hip/hip_runtime.h>
#include <cstdint>
#include <cstddef>

// ---------- types ----------
typedef __bf16 bf16x8 __attribute__((ext_vector_type(8)));
typedef float f32x4 __attribute__((ext_vector_type(4)));

__device__ static inline unsigned short f32_to_bf16_rne(float f) {
  unsigned int u = __float_as_uint(f);
  unsigned int r = 0x7FFFu + ((u >> 16) & 1u);
  return (unsigned short)((u + r) >> 16);
}

__device__ static inline void async16(const void* g, void* l) {
  __builtin_amdgcn_global_load_lds(
      (const __attribute__((address_space(1))) void*)g,
      (__attribute__((address_space(3))) void*)l,
      16, 0, 0);
}

// ---------- prep: U_t[j][i] = bf16(U[i][j]) for i,j < 1024 ----------
__global__ __launch_bounds__(256) void prep_U(const float* __restrict__ U,
                                              unsigned short* __restrict__ Ut) {
  const int j = blockIdx.x;
  for (int i = threadIdx.x; i < 1024; i += 256)
    Ut[(size_t)j * 1024 + i] = f32_to_bf16_rne(U[(size_t)i * 1025 + j]);
}

// ---------- prep: cast D,H rows to bf16; c[r], t[r] biases ----------
// c[r] = sum_i D[r,i]*U[i,1024] + sum_j H[r,j]*W[j] + W[1024]
// t[r] = sum_i D[r,i]*W[1025+i]
__global__ __launch_bounds__(256) void prep_rows(
    const float* __restrict__ D, const float* __restrict__ H,
    const float* __restrict__ U, const float* __restrict__ W,
    unsigned short* __restrict__ Db, unsigned short* __restrict__ Hb,
    float* __restrict__ cvec, float* __restrict__ tvec) {
  const int r = blockIdx.x;
  const int t = threadIdx.x;
  const size_t base = (size_t)r * 1024;
  const int i = t * 4;

  float4 d4 = *(const float4*)(D + base + i);
  float4 h4 = *(const float4*)(H + base + i);

  ushort4 db, hb;
  db.x = f32_to_bf16_rne(d4.x); db.y = f32_to_bf16_rne(d4.y);
  db.z = f32_to_bf16_rne(d4.z); db.w = f32_to_bf16_rne(d4.w);
  hb.x = f32_to_bf16_rne(h4.x); hb.y = f32_to_bf16_rne(h4.y);
  hb.z = f32_to_bf16_rne(h4.z); hb.w = f32_to_bf16_rne(h4.w);
  *(ushort4*)(Db + base + i) = db;
  *(ushort4*)(Hb + base + i) = hb;

  float cp = d4.x * U[(size_t)(i + 0) * 1025 + 1024] +
             d4.y * U[(size_t)(i + 1) * 1025 + 1024] +
             d4.z * U[(size_t)(i + 2) * 1025 + 1024] +
             d4.w * U[(size_t)(i + 3) * 1025 + 1024] +
             h4.x * W[i + 0] + h4.y * W[i + 1] +
             h4.z * W[i + 2] + h4.w * W[i + 3];
  float tp = d4.x * W[1025 + i + 0] + d4.y * W[1025 + i + 1] +
             d4.z * W[1025 + i + 2] + d4.w * W[1025 + i + 3];

#pragma unroll
  for (int off = 32; off > 0; off >>= 1) {
    cp += __shfl_down(cp, off);
    tp += __shfl_down(tp, off);
  }
  __shared__ float red[8];
  const int lane = t & 63, wv = t >> 6;
  if (lane == 0) { red[wv] = cp; red[4 + wv] = tp; }
  __syncthreads();
  if (t == 0) {
    cvec[r] = red[0] + red[1] + red[2] + red[3] + W[1024];
    tvec[r] = red[4] + red[5] + red[6] + red[7];
  }
}

// ---------- MFMA GEMM: C[m][n] = sum_k A[m][k] * Bt[n][k] ----------
// A: M x K row-major bf16, Bt: N x K row-major bf16. lda = ldb = K, ldc = N.
// FUSED: fp32 out + rowBias[m] + colBias[n]. else: bf16 out, no bias.
// Block tile 128x128, BK=64; 4 waves, each 64x64 (4x4 of 16x16x32 MFMA).
template <bool FUSED>
__global__ __launch_bounds__(256) void gemm_bt(
    const unsigned short* __restrict__ A, const unsigned short* __restrict__ Bt,
    void* __restrict__ Cv, const float* __restrict__ rowBias,
    const float* __restrict__ colBias, int M, int N, int K,
    long sA, long sB, long sC) {
  __shared__ unsigned short As[128 * 64];
  __shared__ unsigned short Bs[128 * 64];

  const int tid = threadIdx.x;
  const int lane = tid & 63;
  const int wave = tid >> 6;
  const int wm = wave >> 1, wn = wave & 1;
  const int bz = blockIdx.z;
  const int m0 = blockIdx.y * 128;
  const int n0 = blockIdx.x * 128;

  const unsigned short* Ab = A + (size_t)bz * (size_t)sA;
  const unsigned short* Bb = Bt + (size_t)bz * (size_t)sB;

  size_t aOff[4], bOff[4];
  int ldsOff[4];
#pragma unroll
  for (int q = 0; q < 4; ++q) {
    int e = (q * 256 + tid) * 8;          // bf16 element index in 128x64 tile
    ldsOff[q] = e;
    aOff[q] = (size_t)(m0 + (e >> 6)) * K + (e & 63);
    bOff[q] = (size_t)(n0 + (e >> 6)) * K + (e & 63);
  }

  const f32x4 zero = {0.0f, 0.0f, 0.0f, 0.0f};
  f32x4 acc[4][4];
#pragma unroll
  for (int i = 0; i < 4; ++i)
#pragma unroll
    for (int j = 0; j < 4; ++j) acc[i][j] = zero;

  const int rr = lane & 15;
  const int qd = lane >> 4;
  const int aBase = (wm * 64 + rr) * 64 + qd * 8;
  const int bBase = (wn * 64 + rr) * 64 + qd * 8;

  for (int k0 = 0; k0 < K; k0 += 64) {
#pragma unroll
    for (int q = 0; q < 4; ++q) async16(Ab + aOff[q] + k0, &As[ldsOff[q]]);
#pragma unroll
    for (int q = 0; q < 4; ++q) async16(Bb + bOff[q] + k0, &Bs[ldsOff[q]]);
    __syncthreads();

#pragma unroll
    for (int kk = 0; kk < 64; kk += 32) {
      bf16x8 af[4], bfr[4];
#pragma unroll
      for (int mt = 0; mt < 4; ++mt)
        af[mt] = *(const bf16x8*)&As[aBase + mt * 16 * 64 + kk];
#pragma unroll
      for (int nt = 0; nt < 4; ++nt)
        bfr[nt] = *(const bf16x8*)&Bs[bBase + nt * 16 * 64 + kk];
#pragma unroll
      for (int mt = 0; mt < 4; ++mt)
#pragma unroll
        for (int nt = 0; nt < 4; ++nt)
          acc[mt][nt] = __builtin_amdgcn_mfma_f32_16x16x32_bf16(
              af[mt], bfr[nt], acc[mt][nt], 0, 0, 0);
    }
    __syncthreads();
  }

  // epilogue: C/D layout col=lane&15, row=(lane>>4)*4+reg
  const int cl = lane & 15;
  const int rq = (lane >> 4) * 4;
  if constexpr (FUSED) {
    float* Cf = (float*)Cv + (size_t)bz * (size_t)sC;
#pragma unroll
    for (int mt = 0; mt < 4; ++mt) {
      const int rbase = wm * 64 + mt * 16 + rq;
#pragma unroll
      for (int nt = 0; nt < 4; ++nt) {
        const int c = n0 + wn * 64 + nt * 16 + cl;
        const float cb = colBias[(size_t)bz * N + c];
#pragma unroll
        for (int r = 0; r < 4; ++r) {
          const int gr = m0 + rbase + r;
          Cf[(size_t)gr * N + c] =
              acc[mt][nt][r] + rowBias[(size_t)bz * M + gr] + cb;
        }
      }
    }
  } else {
    unsigned short* Cu = (unsigned short*)Cv;
#pragma unroll
    for (int mt = 0; mt < 4; ++mt) {
      const int rbase = wm * 64 + mt * 16 + rq;
#pragma unroll
      for (int nt = 0; nt < 4; ++nt) {
        const int c = n0 + wn * 64 + nt * 16 + cl;
#pragma unroll
        for (int r = 0; r < 4; ++r) {
          const int gr = m0 + rbase + r;
          Cu[(size_t)gr * N + c] = f32_to_bf16_rne(acc[mt][nt][r]);
        }
      }
    }
  }
}

// ---------- launch ----------
extern "C" void kernel_launch(void* const* d_in, const int* in_sizes, int n_in,
                              void* d_out, int out_size, void* d_ws,
                              size_t ws_size, hipStream_t stream) {
  const float* D = (const float*)d_in[0];  // (64,512,1024)
  const float* H = (const float*)d_in[1];  // (64,512,1024)
  const float* U = (const float*)d_in[2];  // (1024,1025)
  const float* W = (const float*)d_in[3];  // (2049,)
  float* out = (float*)d_out;              // (64,512,512)

  char* ws = (char*)d_ws;
  const size_t SZ = (size_t)32768 * 1024 * 2;  // 64 MiB per bf16 matrix
  unsigned short* Db = (unsigned short*)(ws);
  unsigned short* Hb = (unsigned short*)(ws + SZ);
  unsigned short* DU = (unsigned short*)(ws + 2 * SZ);
  unsigned short* Ut = (unsigned short*)(ws + 3 * SZ);
  float* cvec = (float*)(ws + 3 * SZ + (size_t)1024 * 1024 * 2);
  float* tvec = cvec + 32768;

  prep_U<<<dim3(1024), dim3(256), 0, stream>>>(U, Ut);
  prep_rows<<<dim3(32768), dim3(256), 0, stream>>>(D, H, U, W, Db, Hb, cvec, tvec);

  // GEMM1: DU[r][j] = sum_i D[r][i] * U[i][j]   (M=32768, N=1024, K=1024)
  gemm_bt<false><<<dim3(8, 256, 1), dim3(256), 0, stream>>>(
      Db, Ut, (void*)DU, nullptr, nullptr, 32768, 1024, 1024, 0, 0, 0);

  // GEMM2: out[b][x][y] = sum_j DU[b,x,j]*H[b,y,j] + c[b,x] + t[b,y]
  gemm_bt<true><<<dim3(4, 4, 64), dim3(256), 0, stream>>>(
      DU, Hb, (void*)out, cvec, tvec, 512, 512, 1024,
      (long)512 * 1024, (long)512 * 1024, (long)512 * 512);
}

// Round 2
// 486.035 us; speedup vs baseline: 1.3237x; 1.3237x over previous
//
#include <hip/hip_runtime.h>
#include <cstdint>
#include <cstddef>

// ---------- types ----------
typedef __bf16 bf16x8 __attribute__((ext_vector_type(8)));
typedef float f32x4 __attribute__((ext_vector_type(4)));

__device__ static inline unsigned short f32_to_bf16_rne(float f) {
  unsigned int u = __float_as_uint(f);
  unsigned int r = 0x7FFFu + ((u >> 16) & 1u);
  return (unsigned short)((u + r) >> 16);
}

__device__ static inline void async16(const void* g, void* l) {
  __builtin_amdgcn_global_load_lds(
      (const __attribute__((address_space(1))) void*)g,
      (__attribute__((address_space(3))) void*)l,
      16, 0, 0);
}

// ---------- prep: Ucol[i] = U[i][1024] (contiguous fp32) ----------
__global__ __launch_bounds__(256) void prep_Ucol(const float* __restrict__ U,
                                                 float* __restrict__ Ucol) {
  const int i = blockIdx.x * 256 + threadIdx.x;
  Ucol[i] = U[(size_t)i * 1025 + 1024];
}

// ---------- prep: U_t[j][i] = bf16(U[i][j]), LDS-tiled transpose ----------
__global__ __launch_bounds__(256) void prep_U(const float* __restrict__ U,
                                              unsigned short* __restrict__ Ut) {
  __shared__ float tile[32][33];
  const int i0 = blockIdx.y * 32, j0 = blockIdx.x * 32;
  const int tx = threadIdx.x & 31, ty = threadIdx.x >> 5;  // 32 x 8
#pragma unroll
  for (int r = 0; r < 32; r += 8)
    tile[ty + r][tx] = U[(size_t)(i0 + ty + r) * 1025 + j0 + tx];
  __syncthreads();
#pragma unroll
  for (int r = 0; r < 32; r += 8)
    Ut[(size_t)(j0 + ty + r) * 1024 + i0 + tx] =
        f32_to_bf16_rne(tile[tx][ty + r]);
}

// ---------- prep: cast D,H rows to bf16; c[r], t[r] biases ----------
// c[r] = sum_i D[r,i]*Ucol[i] + sum_j H[r,j]*W[j] + W[1024]
// t[r] = sum_i D[r,i]*W[1025+i]
__global__ __launch_bounds__(256) void prep_rows(
    const float* __restrict__ D, const float* __restrict__ H,
    const float* __restrict__ Ucol, const float* __restrict__ W,
    unsigned short* __restrict__ Db, unsigned short* __restrict__ Hb,
    float* __restrict__ cvec, float* __restrict__ tvec) {
  const int r = blockIdx.x;
  const int t = threadIdx.x;
  const size_t base = (size_t)r * 1024;
  const int i = t * 4;

  float4 d4 = *(const float4*)(D + base + i);
  float4 h4 = *(const float4*)(H + base + i);
  float4 uc = *(const float4*)(Ucol + i);
  float4 wh = *(const float4*)(W + i);
  float4 wd = *(const float4*)(W + 1025 + i);

  ushort4 db, hb;
  db.x = f32_to_bf16_rne(d4.x); db.y = f32_to_bf16_rne(d4.y);
  db.z = f32_to_bf16_rne(d4.z); db.w = f32_to_bf16_rne(d4.w);
  hb.x = f32_to_bf16_rne(h4.x); hb.y = f32_to_bf16_rne(h4.y);
  hb.z = f32_to_bf16_rne(h4.z); hb.w = f32_to_bf16_rne(h4.w);
  *(ushort4*)(Db + base + i) = db;
  *(ushort4*)(Hb + base + i) = hb;

  float cp = d4.x * uc.x + d4.y * uc.y + d4.z * uc.z + d4.w * uc.w +
             h4.x * wh.x + h4.y * wh.y + h4.z * wh.z + h4.w * wh.w;
  float tp = d4.x * wd.x + d4.y * wd.y + d4.z * wd.z + d4.w * wd.w;

#pragma unroll
  for (int off = 32; off > 0; off >>= 1) {
    cp += __shfl_down(cp, off);
    tp += __shfl_down(tp, off);
  }
  __shared__ float red[8];
  const int lane = t & 63, wv = t >> 6;
  if (lane == 0) { red[wv] = cp; red[4 + wv] = tp; }
  __syncthreads();
  if (t == 0) {
    cvec[r] = red[0] + red[1] + red[2] + red[3] + W[1024];
    tvec[r] = red[4] + red[5] + red[6] + red[7];
  }
}

// ---------- MFMA GEMM: C[m][n] = sum_k A[m][k] * Bt[n][k] ----------
// A: M x K row-major bf16, Bt: N x K row-major bf16. lda = ldb = K, ldc = N.
// FUSED: fp32 out + rowBias[m] + colBias[n]. else: bf16 out, no bias.
// Block tile 128x128, BK=64; 4 waves, each 64x64 (4x4 of 16x16x32 MFMA).
template <bool FUSED>
__global__ __launch_bounds__(256) void gemm_bt(
    const unsigned short* __restrict__ A, const unsigned short* __restrict__ Bt,
    void* __restrict__ Cv, const float* __restrict__ rowBias,
    const float* __restrict__ colBias, int M, int N, int K,
    long sA, long sB, long sC) {
  __shared__ unsigned short As[128 * 64];
  __shared__ unsigned short Bs[128 * 64];

  const int tid = threadIdx.x;
  const int lane = tid & 63;
  const int wave = tid >> 6;
  const int wm = wave >> 1, wn = wave & 1;
  const int bz = blockIdx.z;
  const int m0 = blockIdx.y * 128;
  const int n0 = blockIdx.x * 128;

  const unsigned short* Ab = A + (size_t)bz * (size_t)sA;
  const unsigned short* Bb = Bt + (size_t)bz * (size_t)sB;

  size_t aOff[4], bOff[4];
  int ldsOff[4];
#pragma unroll
  for (int q = 0; q < 4; ++q) {
    int e = (q * 256 + tid) * 8;          // bf16 element index in 128x64 tile
    ldsOff[q] = e;
    aOff[q] = (size_t)(m0 + (e >> 6)) * K + (e & 63);
    bOff[q] = (size_t)(n0 + (e >> 6)) * K + (e & 63);
  }

  const f32x4 zero = {0.0f, 0.0f, 0.0f, 0.0f};
  f32x4 acc[4][4];
#pragma unroll
  for (int i = 0; i < 4; ++i)
#pragma unroll
    for (int j = 0; j < 4; ++j) acc[i][j] = zero;

  const int rr = lane & 15;
  const int qd = lane >> 4;
  const int aBase = (wm * 64 + rr) * 64 + qd * 8;
  const int bBase = (wn * 64 + rr) * 64 + qd * 8;

  for (int k0 = 0; k0 < K; k0 += 64) {
#pragma unroll
    for (int q = 0; q < 4; ++q) async16(Ab + aOff[q] + k0, &As[ldsOff[q]]);
#pragma unroll
    for (int q = 0; q < 4; ++q) async16(Bb + bOff[q] + k0, &Bs[ldsOff[q]]);
    __syncthreads();

#pragma unroll
    for (int kk = 0; kk < 64; kk += 32) {
      bf16x8 af[4], bfr[4];
#pragma unroll
      for (int mt = 0; mt < 4; ++mt)
        af[mt] = *(const bf16x8*)&As[aBase + mt * 16 * 64 + kk];
#pragma unroll
      for (int nt = 0; nt < 4; ++nt)
        bfr[nt] = *(const bf16x8*)&Bs[bBase + nt * 16 * 64 + kk];
#pragma unroll
      for (int mt = 0; mt < 4; ++mt)
#pragma unroll
        for (int nt = 0; nt < 4; ++nt)
          acc[mt][nt] = __builtin_amdgcn_mfma_f32_16x16x32_bf16(
              af[mt], bfr[nt], acc[mt][nt], 0, 0, 0);
    }
    __syncthreads();
  }

  // epilogue: C/D layout col=lane&15, row=(lane>>4)*4+reg
  const int cl = lane & 15;
  const int rq = (lane >> 4) * 4;
  if constexpr (FUSED) {
    float* Cf = (float*)Cv + (size_t)bz * (size_t)sC;
#pragma unroll
    for (int mt = 0; mt < 4; ++mt) {
      const int rbase = wm * 64 + mt * 16 + rq;
#pragma unroll
      for (int nt = 0; nt < 4; ++nt) {
        const int c = n0 + wn * 64 + nt * 16 + cl;
        const float cb = colBias[(size_t)bz * N + c];
#pragma unroll
        for (int r = 0; r < 4; ++r) {
          const int gr = m0 + rbase + r;
          Cf[(size_t)gr * N + c] =
              acc[mt][nt][r] + rowBias[(size_t)bz * M + gr] + cb;
        }
      }
    }
  } else {
    unsigned short* Cu = (unsigned short*)Cv;
#pragma unroll
    for (int mt = 0; mt < 4; ++mt) {
      const int rbase = wm * 64 + mt * 16 + rq;
#pragma unroll
      for (int nt = 0; nt < 4; ++nt) {
        const int c = n0 + wn * 64 + nt * 16 + cl;
#pragma unroll
        for (int r = 0; r < 4; ++r) {
          const int gr = m0 + rbase + r;
          Cu[(size_t)gr * N + c] = f32_to_bf16_rne(acc[mt][nt][r]);
        }
      }
    }
  }
}

// ---------- launch ----------
extern "C" void kernel_launch(void* const* d_in, const int* in_sizes, int n_in,
                              void* d_out, int out_size, void* d_ws,
                              size_t ws_size, hipStream_t stream) {
  const float* D = (const float*)d_in[0];  // (64,512,1024)
  const float* H = (const float*)d_in[1];  // (64,512,1024)
  const float* U = (const float*)d_in[2];  // (1024,1025)
  const float* W = (const float*)d_in[3];  // (2049,)
  float* out = (float*)d_out;              // (64,512,512)

  char* ws = (char*)d_ws;
  const size_t SZ = (size_t)32768 * 1024 * 2;  // 64 MiB per bf16 matrix
  unsigned short* Db = (unsigned short*)(ws);
  unsigned short* Hb = (unsigned short*)(ws + SZ);
  unsigned short* DU = (unsigned short*)(ws + 2 * SZ);
  unsigned short* Ut = (unsigned short*)(ws + 3 * SZ);
  float* cvec = (float*)(ws + 3 * SZ + (size_t)1024 * 1024 * 2);
  float* tvec = cvec + 32768;
  float* Ucol = tvec + 32768;

  prep_Ucol<<<dim3(4), dim3(256), 0, stream>>>(U, Ucol);
  prep_U<<<dim3(32, 32), dim3(256), 0, stream>>>(U, Ut);
  prep_rows<<<dim3(32768), dim3(256), 0, stream>>>(D, H, Ucol, W, Db, Hb, cvec, tvec);

  // GEMM1: DU[r][j] = sum_i D[r][i] * U[i][j]   (M=32768, N=1024, K=1024)
  gemm_bt<false><<<dim3(8, 256, 1), dim3(256), 0, stream>>>(
      Db, Ut, (void*)DU, nullptr, nullptr, 32768, 1024, 1024, 0, 0, 0);

  // GEMM2: out[b][x][y] = sum_j DU[b,x,j]*H[b,y,j] + c[b,x] + t[b,y]
  gemm_bt<true><<<dim3(4, 4, 64), dim3(256), 0, stream>>>(
      DU, Hb, (void*)out, cvec, tvec, 512, 512, 1024,
      (long)512 * 1024, (long)512 * 1024, (long)512 * 512);
}

// Round 3
// 454.401 us; speedup vs baseline: 1.4158x; 1.0696x over previous
//
#include <hip/hip_runtime.h>
#include <cstdint>
#include <cstddef>

// ---------- types ----------
typedef __bf16 bf16x8 __attribute__((ext_vector_type(8)));
typedef float f32x4 __attribute__((ext_vector_type(4)));

__device__ static inline unsigned short f32_to_bf16_rne(float f) {
  unsigned int u = __float_as_uint(f);
  unsigned int r = 0x7FFFu + ((u >> 16) & 1u);
  return (unsigned short)((u + r) >> 16);
}

__device__ static inline void async16(const void* g, void* l) {
  __builtin_amdgcn_global_load_lds(
      (const __attribute__((address_space(1))) void*)g,
      (__attribute__((address_space(3))) void*)l,
      16, 0, 0);
}

// ---------- prep: Ucol[i] = U[i][1024] (contiguous fp32) ----------
__global__ __launch_bounds__(256) void prep_Ucol(const float* __restrict__ U,
                                                 float* __restrict__ Ucol) {
  const int i = blockIdx.x * 256 + threadIdx.x;
  Ucol[i] = U[(size_t)i * 1025 + 1024];
}

// ---------- prep: U_t[j][i] = bf16(U[i][j]), LDS-tiled transpose ----------
__global__ __launch_bounds__(256) void prep_U(const float* __restrict__ U,
                                              unsigned short* __restrict__ Ut) {
  __shared__ float tile[32][33];
  const int i0 = blockIdx.y * 32, j0 = blockIdx.x * 32;
  const int tx = threadIdx.x & 31, ty = threadIdx.x >> 5;  // 32 x 8
#pragma unroll
  for (int r = 0; r < 32; r += 8)
    tile[ty + r][tx] = U[(size_t)(i0 + ty + r) * 1025 + j0 + tx];
  __syncthreads();
#pragma unroll
  for (int r = 0; r < 32; r += 8)
    Ut[(size_t)(j0 + ty + r) * 1024 + i0 + tx] =
        f32_to_bf16_rne(tile[tx][ty + r]);
}

// ---------- prep: cast D,H rows to bf16; c[r], t[r] biases ----------
__global__ __launch_bounds__(256) void prep_rows(
    const float* __restrict__ D, const float* __restrict__ H,
    const float* __restrict__ Ucol, const float* __restrict__ W,
    unsigned short* __restrict__ Db, unsigned short* __restrict__ Hb,
    float* __restrict__ cvec, float* __restrict__ tvec) {
  const int r = blockIdx.x;
  const int t = threadIdx.x;
  const size_t base = (size_t)r * 1024;
  const int i = t * 4;

  float4 d4 = *(const float4*)(D + base + i);
  float4 h4 = *(const float4*)(H + base + i);
  float4 uc = *(const float4*)(Ucol + i);
  float4 wh = *(const float4*)(W + i);
  float4 wd = *(const float4*)(W + 1025 + i);

  ushort4 db, hb;
  db.x = f32_to_bf16_rne(d4.x); db.y = f32_to_bf16_rne(d4.y);
  db.z = f32_to_bf16_rne(d4.z); db.w = f32_to_bf16_rne(d4.w);
  hb.x = f32_to_bf16_rne(h4.x); hb.y = f32_to_bf16_rne(h4.y);
  hb.z = f32_to_bf16_rne(h4.z); hb.w = f32_to_bf16_rne(h4.w);
  *(ushort4*)(Db + base + i) = db;
  *(ushort4*)(Hb + base + i) = hb;

  float cp = d4.x * uc.x + d4.y * uc.y + d4.z * uc.z + d4.w * uc.w +
             h4.x * wh.x + h4.y * wh.y + h4.z * wh.z + h4.w * wh.w;
  float tp = d4.x * wd.x + d4.y * wd.y + d4.z * wd.z + d4.w * wd.w;

#pragma unroll
  for (int off = 32; off > 0; off >>= 1) {
    cp += __shfl_down(cp, off);
    tp += __shfl_down(tp, off);
  }
  __shared__ float red[8];
  const int lane = t & 63, wv = t >> 6;
  if (lane == 0) { red[wv] = cp; red[4 + wv] = tp; }
  __syncthreads();
  if (t == 0) {
    cvec[r] = red[0] + red[1] + red[2] + red[3] + W[1024];
    tvec[r] = red[4] + red[5] + red[6] + red[7];
  }
}

// ---------- MFMA GEMM: C[m][n] = sum_k A[m][k] * Bt[n][k] ----------
// XOR-swizzled LDS: slot chunk ch of row holds global chunk ch^(row&7).
// Staging permutes per-lane global sources (LDS dest stays lane-contiguous,
// satisfying global_load_lds's wave-uniform-base + lane*16 constraint).
template <bool FUSED>
__global__ __launch_bounds__(256) void gemm_bt(
    const unsigned short* __restrict__ A, const unsigned short* __restrict__ Bt,
    void* __restrict__ Cv, const float* __restrict__ rowBias,
    const float* __restrict__ colBias, int M, int N, int K,
    long sA, long sB, long sC) {
  __shared__ unsigned short As[128 * 64];
  __shared__ unsigned short Bs[128 * 64];

  const int tid = threadIdx.x;
  const int lane = tid & 63;
  const int wave = tid >> 6;
  const int wm = wave >> 1, wn = wave & 1;
  const int bz = blockIdx.z;
  const int m0 = blockIdx.y * 128;
  const int n0 = blockIdx.x * 128;

  const unsigned short* Ab = A + (size_t)bz * (size_t)sA;
  const unsigned short* Bb = Bt + (size_t)bz * (size_t)sB;

  size_t aOff[4], bOff[4];
  int ldsOff[4];
#pragma unroll
  for (int q = 0; q < 4; ++q) {
    int e = (q * 256 + tid) * 8;   // bf16 element index in 128x64 tile
    int row = e >> 6;              // tile-local row 0..127
    int ch = (e >> 3) & 7;         // chunk-of-8 within row
    int chSw = ch ^ (row & 7);     // swizzled source chunk
    ldsOff[q] = e;
    aOff[q] = (size_t)(m0 + row) * K + chSw * 8;
    bOff[q] = (size_t)(n0 + row) * K + chSw * 8;
  }

  const f32x4 zero = {0.0f, 0.0f, 0.0f, 0.0f};
  f32x4 acc[4][4];
#pragma unroll
  for (int i = 0; i < 4; ++i)
#pragma unroll
    for (int j = 0; j < 4; ++j) acc[i][j] = zero;

  const int rr = lane & 15;
  const int qd = lane >> 4;
  const int c0 = qd ^ (rr & 7);            // swizzled base chunk
  const int aRow = (wm * 64 + rr) * 64;
  const int bRow = (wn * 64 + rr) * 64;

  for (int k0 = 0; k0 < K; k0 += 64) {
#pragma unroll
    for (int q = 0; q < 4; ++q) async16(Ab + aOff[q] + k0, &As[ldsOff[q]]);
#pragma unroll
    for (int q = 0; q < 4; ++q) async16(Bb + bOff[q] + k0, &Bs[ldsOff[q]]);
    __syncthreads();

#pragma unroll
    for (int kk = 0; kk < 64; kk += 32) {
      const int co = (c0 ^ (kk >> 3)) * 8;  // kk=0 -> c0, kk=32 -> c0^4
      bf16x8 af[4], bfr[4];
#pragma unroll
      for (int mt = 0; mt < 4; ++mt)
        af[mt] = *(const bf16x8*)&As[aRow + mt * 16 * 64 + co];
#pragma unroll
      for (int nt = 0; nt < 4; ++nt)
        bfr[nt] = *(const bf16x8*)&Bs[bRow + nt * 16 * 64 + co];
#pragma unroll
      for (int mt = 0; mt < 4; ++mt)
#pragma unroll
        for (int nt = 0; nt < 4; ++nt)
          acc[mt][nt] = __builtin_amdgcn_mfma_f32_16x16x32_bf16(
              af[mt], bfr[nt], acc[mt][nt], 0, 0, 0);
    }
    __syncthreads();
  }

  // epilogue: C/D layout col=lane&15, row=(lane>>4)*4+reg
  const int cl = lane & 15;
  const int rq = (lane >> 4) * 4;
  if constexpr (FUSED) {
    float* Cf = (float*)Cv + (size_t)bz * (size_t)sC;
#pragma unroll
    for (int mt = 0; mt < 4; ++mt) {
      const int rbase = wm * 64 + mt * 16 + rq;
#pragma unroll
      for (int nt = 0; nt < 4; ++nt) {
        const int c = n0 + wn * 64 + nt * 16 + cl;
        const float cb = colBias[(size_t)bz * N + c];
#pragma unroll
        for (int r = 0; r < 4; ++r) {
          const int gr = m0 + rbase + r;
          Cf[(size_t)gr * N + c] =
              acc[mt][nt][r] + rowBias[(size_t)bz * M + gr] + cb;
        }
      }
    }
  } else {
    unsigned short* Cu = (unsigned short*)Cv;
#pragma unroll
    for (int mt = 0; mt < 4; ++mt) {
      const int rbase = wm * 64 + mt * 16 + rq;
#pragma unroll
      for (int nt = 0; nt < 4; ++nt) {
        const int c = n0 + wn * 64 + nt * 16 + cl;
#pragma unroll
        for (int r = 0; r < 4; ++r) {
          const int gr = m0 + rbase + r;
          Cu[(size_t)gr * N + c] = f32_to_bf16_rne(acc[mt][nt][r]);
        }
      }
    }
  }
}

// ---------- launch ----------
extern "C" void kernel_launch(void* const* d_in, const int* in_sizes, int n_in,
                              void* d_out, int out_size, void* d_ws,
                              size_t ws_size, hipStream_t stream) {
  const float* D = (const float*)d_in[0];  // (64,512,1024)
  const float* H = (const float*)d_in[1];  // (64,512,1024)
  const float* U = (const float*)d_in[2];  // (1024,1025)
  const float* W = (const float*)d_in[3];  // (2049,)
  float* out = (float*)d_out;              // (64,512,512)

  char* ws = (char*)d_ws;
  const size_t SZ = (size_t)32768 * 1024 * 2;  // 64 MiB per bf16 matrix
  unsigned short* Db = (unsigned short*)(ws);
  unsigned short* Hb = (unsigned short*)(ws + SZ);
  unsigned short* DU = (unsigned short*)(ws + 2 * SZ);
  unsigned short* Ut = (unsigned short*)(ws + 3 * SZ);
  float* cvec = (float*)(ws + 3 * SZ + (size_t)1024 * 1024 * 2);
  float* tvec = cvec + 32768;
  float* Ucol = tvec + 32768;

  prep_Ucol<<<dim3(4), dim3(256), 0, stream>>>(U, Ucol);
  prep_U<<<dim3(32, 32), dim3(256), 0, stream>>>(U, Ut);
  prep_rows<<<dim3(32768), dim3(256), 0, stream>>>(D, H, Ucol, W, Db, Hb, cvec, tvec);

  // GEMM1: DU[r][j] = sum_i D[r][i] * U[i][j]   (M=32768, N=1024, K=1024)
  gemm_bt<false><<<dim3(8, 256, 1), dim3(256), 0, stream>>>(
      Db, Ut, (void*)DU, nullptr, nullptr, 32768, 1024, 1024, 0, 0, 0);

  // GEMM2: out[b][x][y] = sum_j DU[b,x,j]*H[b,y,j] + c[b,x] + t[b,y]
  gemm_bt<true><<<dim3(4, 4, 64), dim3(256), 0, stream>>>(
      DU, Hb, (void*)out, cvec, tvec, 512, 512, 1024,
      (long)512 * 1024, (long)512 * 1024, (long)512 * 512);
}